// Round 21
// baseline (581.964 us; speedup 1.0000x reference)
//
#include <hip/hip_runtime.h>
#include <math.h>

constexpr int Lseq = 4096, Dm = 1024, H = 4, DK = 512, DV = 1024;
constexpr int DQH = 128, DVH = 256, CH = 64, ROWS = 4 * 4096;
constexpr int QKS = 1024;   // combined q|k row stride

typedef unsigned short u16;
struct alignas(16) us8 { u16 u[8]; };
typedef __attribute__((ext_vector_type(8))) short bf16x8;
typedef __attribute__((ext_vector_type(4))) float f32x4;

__device__ __forceinline__ float sig_(float x) { return 1.f / (1.f + expf(-x)); }
__device__ __forceinline__ float b2f(u16 u) {
  union { float f; unsigned v; } x; x.v = (unsigned)u << 16; return x.f;
}
__device__ __forceinline__ u16 f2b(float f) {   // round-to-nearest-even
  union { float f; unsigned v; } x; x.f = f;
  unsigned r = x.v + 0x7fffu + ((x.v >> 16) & 1u);
  return (u16)(r >> 16);
}
__device__ __forceinline__ void gld16(const u16* g, u16* l) {
  __builtin_amdgcn_global_load_lds(
      (const __attribute__((address_space(1))) void*)g,
      (__attribute__((address_space(3))) void*)l, 16, 0, 0);
}

__global__ void ws_sentinel_kernel(float* out, float v) { out[0] = v; }

// ---- 1. PROLOGUE: conv+silu (0..8191) + weight cvt/T (8192..10239) ----
__global__ __launch_bounds__(256) void prologue_kernel(
    const float* __restrict__ x, const float* __restrict__ w, u16* __restrict__ h,
    const float* __restrict__ Wq, const float* __restrict__ Wk,
    const float* __restrict__ Wv, const float* __restrict__ Wg,
    const float* __restrict__ Wo,
    u16* wq16, u16* wk16, u16* wv16, u16* wg16, u16* wo16) {
  __shared__ u16 T[32][66];
  const int t = threadIdx.x;
  if (blockIdx.x < 8192) {
    int idx = blockIdx.x * 256 + t;
    int d8 = (idx & 127) << 3;
    int row = idx >> 7;
    int l = row & (Lseq - 1), b = row >> 12;
    const float* xb = x + ((size_t)b << 22);
    float4 wv_[8];
#pragma unroll
    for (int j = 0; j < 2; ++j) {
      wv_[j * 4 + 0] = *(const float4*)&w[d8 * 4 + j * 16 + 0];
      wv_[j * 4 + 1] = *(const float4*)&w[d8 * 4 + j * 16 + 4];
      wv_[j * 4 + 2] = *(const float4*)&w[d8 * 4 + j * 16 + 8];
      wv_[j * 4 + 3] = *(const float4*)&w[d8 * 4 + j * 16 + 12];
    }
    float acc[8] = {0, 0, 0, 0, 0, 0, 0, 0};
#pragma unroll
    for (int i = 0; i < 4; ++i) {
      int li = l - 3 + i;
      if (li >= 0) {
        float4 x0 = *(const float4*)&xb[((size_t)li << 10) + d8];
        float4 x1 = *(const float4*)&xb[((size_t)li << 10) + d8 + 4];
        acc[0] = fmaf(((const float*)&wv_[0])[i], x0.x, acc[0]);
        acc[1] = fmaf(((const float*)&wv_[1])[i], x0.y, acc[1]);
        acc[2] = fmaf(((const float*)&wv_[2])[i], x0.z, acc[2]);
        acc[3] = fmaf(((const float*)&wv_[3])[i], x0.w, acc[3]);
        acc[4] = fmaf(((const float*)&wv_[4])[i], x1.x, acc[4]);
        acc[5] = fmaf(((const float*)&wv_[5])[i], x1.y, acc[5]);
        acc[6] = fmaf(((const float*)&wv_[6])[i], x1.z, acc[6]);
        acc[7] = fmaf(((const float*)&wv_[7])[i], x1.w, acc[7]);
      }
    }
    us8 o;
#pragma unroll
    for (int j = 0; j < 8; ++j) o.u[j] = f2b(acc[j] * sig_(acc[j]));
    *(us8*)&h[(size_t)row * Dm + d8] = o;
    return;
  }
  int bid = blockIdx.x - 8192;
  const float* in; u16* out; int N, K, b0;
  if (bid < 256)       { in = Wq; out = wq16; N = DK; K = Dm; b0 = bid; }
  else if (bid < 512)  { in = Wk; out = wk16; N = DK; K = Dm; b0 = bid - 256; }
  else if (bid < 1024) { in = Wv; out = wv16; N = DV; K = Dm; b0 = bid - 512; }
  else if (bid < 1536) { in = Wg; out = wg16; N = DV; K = Dm; b0 = bid - 1024; }
  else                 { in = Wo; out = wo16; N = Dm; K = DV; b0 = bid - 1536; }
  const int nbx = N / 64;
  const int k0 = (b0 / nbx) * 32, n0 = (b0 % nbx) * 64;
#pragma unroll
  for (int i = 0; i < 8; ++i) {
    int idx = t + i * 256;
    int kk = idx >> 6, nn = idx & 63;
    T[kk][nn] = f2b(in[(size_t)(k0 + kk) * N + n0 + nn]);
  }
  __syncthreads();
#pragma unroll
  for (int i = 0; i < 8; ++i) {
    int idx = t + i * 256;
    int kk = idx & 31, nn = idx >> 5;
    out[(size_t)(n0 + nn) * K + k0 + kk] = T[kk][nn];
  }
}

// ---- GEMM body (BK=64 + swizzle), 256 thr ----
template <int MODE>
__device__ __forceinline__ void gemm_body(
    const u16* __restrict__ A, const u16* __restrict__ BT, void* __restrict__ Cv,
    int M, int N, int K, int bid, int nwg, u16* As, u16* Bs) {
  const int tid = threadIdx.x;
  const int wid = tid >> 6, lane = tid & 63;
  const int wr = wid >> 1, wc = wid & 1;
  const int fr = lane & 15, fk = lane >> 4;
  const int nbx = N >> 7;
  const int swz = (bid & 7) * (nwg >> 3) + (bid >> 3);
  const int row0 = (swz / nbx) * 128, col0 = (swz % nbx) * 128;

  int sr[4], sk[4];
#pragma unroll
  for (int i = 0; i < 4; ++i) {
    int s = i * 4 + wid;
    int r = s * 8 + (lane >> 3);
    sr[i] = r;
    sk[i] = ((lane & 7) ^ (r & 7)) << 3;
  }

  f32x4 acc[4][4];
#pragma unroll
  for (int i = 0; i < 4; ++i)
#pragma unroll
    for (int j = 0; j < 4; ++j) acc[i][j] = {0.f, 0.f, 0.f, 0.f};

  for (int k0 = 0; k0 < K; k0 += 64) {
#pragma unroll
    for (int i = 0; i < 4; ++i) {
      const int s = i * 4 + wid;
      gld16(&A[(size_t)(row0 + sr[i]) * K + k0 + sk[i]], &As[s * 512]);
      gld16(&BT[(size_t)(col0 + sr[i]) * K + k0 + sk[i]], &Bs[s * 512]);
    }
    __syncthreads();
#pragma unroll
    for (int kt = 0; kt < 2; ++kt) {
      bf16x8 af[4], bf[4];
#pragma unroll
      for (int mi = 0; mi < 4; ++mi) {
        int row = wr * 64 + mi * 16 + fr;
        af[mi] = *(const bf16x8*)&As[row * 64 + (((kt * 4 + fk) ^ (fr & 7)) << 3)];
      }
#pragma unroll
      for (int ni = 0; ni < 4; ++ni) {
        int row = wc * 64 + ni * 16 + fr;
        bf[ni] = *(const bf16x8*)&Bs[row * 64 + (((kt * 4 + fk) ^ (fr & 7)) << 3)];
      }
#pragma unroll
      for (int mi = 0; mi < 4; ++mi)
#pragma unroll
        for (int ni = 0; ni < 4; ++ni)
          acc[mi][ni] = __builtin_amdgcn_mfma_f32_16x16x32_bf16(
              af[mi], bf[ni], acc[mi][ni], 0, 0, 0);
    }
    __syncthreads();
  }

  if (MODE == 2) {
    __shared__ float ssh[2][128];
#pragma unroll
    for (int mi = 0; mi < 4; ++mi)
#pragma unroll
      for (int r = 0; r < 4; ++r) {
        float p = 0.f;
#pragma unroll
        for (int ni = 0; ni < 4; ++ni) p += acc[mi][ni][r] * acc[mi][ni][r];
        p += __shfl_xor(p, 1); p += __shfl_xor(p, 2);
        p += __shfl_xor(p, 4); p += __shfl_xor(p, 8);
        if (fr == 0) ssh[wc][wr * 64 + mi * 16 + fk * 4 + r] = p;
      }
    __syncthreads();
#pragma unroll
    for (int mi = 0; mi < 4; ++mi)
#pragma unroll
      for (int r = 0; r < 4; ++r) {
        int ridx = wr * 64 + mi * 16 + fk * 4 + r;
        float sc = 1.f / fmaxf(sqrtf(ssh[0][ridx] + ssh[1][ridx]), 1e-12f);
#pragma unroll
        for (int ni = 0; ni < 4; ++ni) acc[mi][ni][r] *= sc;
      }
  }

#pragma unroll
  for (int mi = 0; mi < 4; ++mi)
#pragma unroll
    for (int ni = 0; ni < 4; ++ni) {
      int col = col0 + wc * 64 + ni * 16 + fr;
#pragma unroll
      for (int r = 0; r < 4; ++r) {
        int row = row0 + wr * 64 + mi * 16 + fk * 4 + r;
        if (MODE == 1) ((float*)Cv)[(size_t)row * N + col] = acc[mi][ni][r];
        else           ((u16*)Cv)[(size_t)row * N + col] = f2b(acc[mi][ni][r]);
      }
    }
}

__global__ __launch_bounds__(256) void gemm_mfma_kernel(
    const u16* __restrict__ A, const u16* __restrict__ BT, void* __restrict__ Cv,
    int M, int N, int K) {
  __shared__ u16 As[128 * 64];
  __shared__ u16 Bs[128 * 64];
  gemm_body<1>(A, BT, Cv, M, N, K, blockIdx.x, gridDim.x, As, Bs);
}

// ---- 2. PROJECTIONS mega-kernel ----
__global__ __launch_bounds__(256) void proj_kernel(
    const u16* __restrict__ hb, const u16* __restrict__ wqk16,
    const u16* __restrict__ wv16, const float* __restrict__ Wb,
    u16* __restrict__ qk, u16* __restrict__ vb, float* __restrict__ beta) {
  __shared__ u16 As[128 * 64];
  __shared__ u16 Bs[128 * 64];
  const int bid = blockIdx.x;
  if (bid < 1024) {
    gemm_body<2>(hb, wqk16, qk, ROWS, QKS, Dm, bid, 1024, As, Bs);
    return;
  }
  if (bid < 2048) {
    gemm_body<0>(hb, wv16, vb, ROWS, DV, Dm, bid - 1024, 1024, As, Bs);
    return;
  }
  int row = (bid - 2048) * 4 + (threadIdx.x >> 6), lane = threadIdx.x & 63;
  const u16* hrow = hb + (size_t)row * Dm;
  float a0 = 0, a1 = 0, a2 = 0, a3 = 0;
  for (int k0 = 0; k0 < Dm; k0 += 64) {
    float hv = b2f(hrow[k0 + lane]);
    float4 wv = *(const float4*)&Wb[(size_t)(k0 + lane) * 4];
    a0 = fmaf(hv, wv.x, a0); a1 = fmaf(hv, wv.y, a1);
    a2 = fmaf(hv, wv.z, a2); a3 = fmaf(hv, wv.w, a3);
  }
#pragma unroll
  for (int off = 32; off; off >>= 1) {
    a0 += __shfl_down(a0, off); a1 += __shfl_down(a1, off);
    a2 += __shfl_down(a2, off); a3 += __shfl_down(a3, off);
  }
  if (lane == 0) {
    int b = row >> 12, l = row & (Lseq - 1);
    beta[((size_t)(b * H + 0)) * Lseq + l] = sig_(a0);
    beta[((size_t)(b * H + 1)) * Lseq + l] = sig_(a1);
    beta[((size_t)(b * H + 2)) * Lseq + l] = sig_(a2);
    beta[((size_t)(b * H + 3)) * Lseq + l] = sig_(a3);
  }
}

// ---- 5a. delta prep v2 (round-18 proven) ----
__global__ __launch_bounds__(256) void delta_prep_kernel(
    const u16* __restrict__ qk, u16* v, const float* __restrict__ beta,
    u16* __restrict__ Wout, u16* __restrict__ QKout) {
  __shared__ alignas(16) char lds0[18432];
  __shared__ alignas(16) char lds1[18432];
  __shared__ float Bc[64];
  float (*Am)[68] = (float(*)[68])lds0;
  float (*R)[68]  = (float(*)[68])lds1;
  u16 (*Th)[72]  = (u16(*)[72])lds0;
  u16 (*Tl)[72]  = (u16(*)[72])(lds0 + 9216);
  u16 (*XTh)[72] = (u16(*)[72])lds1;
  u16 (*XTl)[72] = (u16(*)[72])(lds1 + 9216);

  const int tid = threadIdx.x;
  const int wid = tid >> 6, lane = tid & 63;
  const int fr = lane & 15, fq = lane >> 4;
  const int bh = blockIdx.x >> 6, ch = blockIdx.x & 63;
  const int b = bh >> 2, hh = bh & 3;
  const int c0 = ch * CH;
  const u16* qbase = qk + (size_t)b * Lseq * QKS + hh * DQH;
  const u16* kbase = qk + (size_t)b * Lseq * QKS + 512 + hh * DQH;
  u16*       vbase = v + (size_t)b * Lseq * DV + hh * DVH;
  const float* bbase = beta + (size_t)bh * Lseq;
  u16* Wrow  = Wout  + ((size_t)bh * Lseq + c0) * DQH;
  u16* QKrow = QKout + ((size_t)bh * Lseq + c0) * CH;

  if (tid < 64) Bc[tid] = bbase[c0 + tid];
  for (int idx = tid; idx < 64 * 64; idx += 256) {
    int r = idx >> 6, c = idx & 63;
    R[r][c] = (r == c) ? 1.f : 0.f;
  }
  __syncthreads();

  {
    const int m0 = wid * 16;
    f32x4 accG[4], accQ[4];
#pragma unroll
    for (int ni = 0; ni < 4; ++ni) {
      accG[ni] = {0.f, 0.f, 0.f, 0.f};
      accQ[ni] = {0.f, 0.f, 0.f, 0.f};
    }
#pragma unroll
    for (int kt = 0; kt < 4; ++kt) {
      bf16x8 afk = *(const bf16x8*)&kbase[(size_t)(c0 + m0 + fr) * QKS + kt * 32 + fq * 8];
      bf16x8 afq = *(const bf16x8*)&qbase[(size_t)(c0 + m0 + fr) * QKS + kt * 32 + fq * 8];
#pragma unroll
      for (int ni = 0; ni < 4; ++ni) {
        bf16x8 bfk = *(const bf16x8*)&kbase[(size_t)(c0 + ni * 16 + fr) * QKS + kt * 32 + fq * 8];
        accG[ni] = __builtin_amdgcn_mfma_f32_16x16x32_bf16(afk, bfk, accG[ni], 0, 0, 0);
        accQ[ni] = __builtin_amdgcn_mfma_f32_16x16x32_bf16(afq, bfk, accQ[ni], 0, 0, 0);
      }
    }
#pragma unroll
    for (int ni = 0; ni < 4; ++ni)
#pragma unroll
      for (int i = 0; i < 4; ++i) {
        int row = m0 + fq * 4 + i, col = ni * 16 + fr;
        float br = Bc[row];
        Am[row][col] = (col < row) ? br * accG[ni][i] : 0.f;
        QKrow[(size_t)row * CH + col] = f2b((col <= row) ? accQ[ni][i] : 0.f);
      }
  }
  __syncthreads();

  for (int rb = 0; rb < 4; ++rb) {
    if (rb > 0) {
      const int c = tid & 63, g = tid >> 6;
      const int R0 = rb * 16, row = R0 + g * 4;
      float s0 = 0, s1 = 0, s2 = 0, s3 = 0;
      for (int m = 0; m < R0; ++m) {
        float uv = R[m][c];
        s0 = fmaf(Am[row + 0][m], uv, s0);
        s1 = fmaf(Am[row + 1][m], uv, s1);
        s2 = fmaf(Am[row + 2][m], uv, s2);
        s3 = fmaf(Am[row + 3][m], uv, s3);
      }
      R[row + 0][c] -= s0; R[row + 1][c] -= s1;
      R[row + 2][c] -= s2; R[row + 3][c] -= s3;
    }
    __syncthreads();
    if (tid < 64) {
      const int c = tid;
      for (int i = 1; i < 16; ++i) {
        const int row = rb * 16 + i;
        float s = R[row][c];
        for (int m = 0; m < i; ++m)
          s = fmaf(-Am[row][rb * 16 + m], R[rb * 16 + m][c], s);
        R[row][c] = s;
      }
    }
    __syncthreads();
  }

  for (int idx = tid; idx < 64 * 64; idx += 256) {
    int r = idx >> 6, c = idx & 63;
    float tv = R[r][c];
    u16 hh2 = f2b(tv);
    Th[r][c] = hh2;
    Tl[r][c] = f2b(tv - b2f(hh2));
  }
  __syncthreads();

  for (int p = 0; p < 6; ++p) {
    const int off = (p < 2) ? p * 64 : (p - 2) * 64;
    for (int idx = tid; idx < 64 * 64; idx += 256) {
      int d = idx & 63, m = idx >> 6;
      float xv;
      if (p < 2) xv = Bc[m] * b2f(kbase[(size_t)(c0 + m) * QKS + off + d]);
      else       xv = Bc[m] * b2f(vbase[(size_t)(c0 + m) * DV + off + d]);
      u16 hh2 = f2b(xv);
      XTh[d][m] = hh2;
      XTl[d][m] = f2b(xv - b2f(hh2));
    }
    __syncthreads();
    f32x4 acc[4];
#pragma unroll
    for (int tn = 0; tn < 4; ++tn) acc[tn] = {0.f, 0.f, 0.f, 0.f};
#pragma unroll
    for (int kt = 0; kt < 2; ++kt) {
      bf16x8 ah = *(const bf16x8*)&Th[wid * 16 + fr][kt * 32 + fq * 8];
      bf16x8 al = *(const bf16x8*)&Tl[wid * 16 + fr][kt * 32 + fq * 8];
#pragma unroll
      for (int tn = 0; tn < 4; ++tn) {
        bf16x8 xh = *(const bf16x8*)&XTh[tn * 16 + fr][kt * 32 + fq * 8];
        bf16x8 xl = *(const bf16x8*)&XTl[tn * 16 + fr][kt * 32 + fq * 8];
        acc[tn] = __builtin_amdgcn_mfma_f32_16x16x32_bf16(ah, xh, acc[tn], 0, 0, 0);
        acc[tn] = __builtin_amdgcn_mfma_f32_16x16x32_bf16(ah, xl, acc[tn], 0, 0, 0);
        acc[tn] = __builtin_amdgcn_mfma_f32_16x16x32_bf16(al, xh, acc[tn], 0, 0, 0);
      }
    }
#pragma unroll
    for (int tn = 0; tn < 4; ++tn)
#pragma unroll
      for (int i = 0; i < 4; ++i) {
        int row = wid * 16 + fq * 4 + i, col = tn * 16 + fr;
        if (p < 2) Wrow[(size_t)row * DQH + off + col] = f2b(-acc[tn][i]);
        else       vbase[(size_t)(c0 + row) * DV + off + col] = f2b(acc[tn][i]);
      }
    __syncthreads();
  }
}

// ---- 5a'. mk: M = K^T·Wneg -> Mb ; Q' = Q + QK·Wneg -> overwrite Wbuf ----
__global__ __launch_bounds__(256) void mk_kernel(
    const u16* __restrict__ qk, u16* Wn, const u16* __restrict__ QKb,
    u16* __restrict__ Mb) {
  __shared__ alignas(16) u16 Kt[128][72];
  __shared__ alignas(16) u16 WT[128][72];
  const int tid = threadIdx.x;
  const int wid = tid >> 6, lane = tid & 63;
  const int fr = lane & 15, fq = lane >> 4;
  const int bh = blockIdx.x >> 6, ch = blockIdx.x & 63;
  const int b = bh >> 2, hh = bh & 3;
  const int c0 = ch * CH;
  const u16* qbase = qk + (size_t)b * Lseq * QKS + hh * DQH;
  const u16* kbase = qk + (size_t)b * Lseq * QKS + 512 + hh * DQH;
  u16* Wrow = Wn + ((size_t)bh * Lseq + c0) * DQH;
  const u16* QKrow = QKb + ((size_t)bh * Lseq + c0) * CH;
  u16* Mrow = Mb + (size_t)(bh * 64 + ch) * (128 * 128);

  // stage K^T and Wneg^T
#pragma unroll
  for (int i = 0; i < 4; ++i) {
    int id = tid + i * 256;
    int r = id & 63, d8 = (id >> 6) << 3;
    us8 kv = *(const us8*)&kbase[(size_t)(c0 + r) * QKS + d8];
#pragma unroll
    for (int j = 0; j < 8; ++j) Kt[d8 + j][r] = kv.u[j];
  }
#pragma unroll
  for (int i = 0; i < 4; ++i) {
    int id = tid + i * 256;
    int r = id >> 4, n8 = (id & 15) << 3;
    us8 wv = *(const us8*)&Wrow[(size_t)r * DQH + n8];
#pragma unroll
    for (int j = 0; j < 8; ++j) WT[n8 + j][r] = wv.u[j];
  }
  __syncthreads();

  // M = K^T·Wneg : wave owns M rows 32*wid..+31
#pragma unroll
  for (int mt = 0; mt < 2; ++mt) {
    const int mrow = 32 * wid + 16 * mt;
    bf16x8 a0 = *(const bf16x8*)&Kt[mrow + fr][fq * 8];
    bf16x8 a1 = *(const bf16x8*)&Kt[mrow + fr][32 + fq * 8];
    f32x4 acc[8];
#pragma unroll
    for (int nt = 0; nt < 8; ++nt) acc[nt] = {0.f, 0.f, 0.f, 0.f};
#pragma unroll
    for (int nt = 0; nt < 8; ++nt) {
      bf16x8 b0 = *(const bf16x8*)&WT[nt * 16 + fr][fq * 8];
      bf16x8 b1 = *(const bf16x8*)&WT[nt * 16 + fr][32 + fq * 8];
      acc[nt] = __builtin_amdgcn_mfma_f32_16x16x32_bf16(a0, b0, acc[nt], 0, 0, 0);
      acc[nt] = __builtin_amdgcn_mfma_f32_16x16x32_bf16(a1, b1, acc[nt], 0, 0, 0);
    }
#pragma unroll
    for (int nt = 0; nt < 8; ++nt)
#pragma unroll
      for (int i = 0; i < 4; ++i)
        Mrow[(size_t)(mrow + fq * 4 + i) * 128 + nt * 16 + fr] = f2b(acc[nt][i]);
  }

  // Q' = Q + QK·Wneg : wave owns rows 16*wid..+15; overwrite Wrow
  {
    const int m0 = 16 * wid;
    bf16x8 a0 = *(const bf16x8*)&QKrow[(size_t)(m0 + fr) * CH + fq * 8];
    bf16x8 a1 = *(const bf16x8*)&QKrow[(size_t)(m0 + fr) * CH + 32 + fq * 8];
    f32x4 acc[8];
#pragma unroll
    for (int nt = 0; nt < 8; ++nt) acc[nt] = {0.f, 0.f, 0.f, 0.f};
#pragma unroll
    for (int nt = 0; nt < 8; ++nt) {
      bf16x8 b0 = *(const bf16x8*)&WT[nt * 16 + fr][fq * 8];
      bf16x8 b1 = *(const bf16x8*)&WT[nt * 16 + fr][32 + fq * 8];
      acc[nt] = __builtin_amdgcn_mfma_f32_16x16x32_bf16(a0, b0, acc[nt], 0, 0, 0);
      acc[nt] = __builtin_amdgcn_mfma_f32_16x16x32_bf16(a1, b1, acc[nt], 0, 0, 0);
    }
    __syncthreads();   // all WT/Kt reads done before overwrite
#pragma unroll
    for (int nt = 0; nt < 8; ++nt)
#pragma unroll
      for (int i = 0; i < 4; ++i) {
        int row = m0 + fq * 4 + i, col = nt * 16 + fr;
        float qv = b2f(qbase[(size_t)(c0 + row) * QKS + col]);
        Wrow[(size_t)row * DQH + col] = f2b(qv + acc[nt][i]);
      }
  }
}

// ---- linearized scan body: S' = S + M·S + Z ; O = Q'·S + QK·U0 ----
__device__ __forceinline__ void scan2_body(
    int sbid, const u16* __restrict__ qk, const u16* __restrict__ Qp,
    const u16* __restrict__ QKb, const u16* __restrict__ Mb, u16* uo,
    u16 (*Kt)[72], u16 (*Sbt_hi)[136], u16 (*Sbt_lo)[136], u16 (*U0t)[72]) {
  const int tid = threadIdx.x;
  const int wid = tid >> 6, lane = tid & 63;
  const int fr = lane & 15, fq = lane >> 4;
  const int m0w = 16 * (wid & 3);
  const int bh = sbid & 15, vblk = sbid >> 4;   // XCD-local bh
  const int b = bh >> 2, hh = bh & 3;
  const u16* kbase = qk + (size_t)b * Lseq * QKS + 512 + hh * DQH;
  const u16* Qpbase = Qp + (size_t)bh * Lseq * DQH;
  const u16* QKbase = QKb + (size_t)bh * Lseq * CH;
  const u16* Mbase = Mb + (size_t)bh * 64 * (128 * 128);
  u16* uobase = uo + (size_t)b * Lseq * DV + hh * DVH + vblk * 16;

  for (int i = tid; i < 16 * 136; i += 512) {
    (&Sbt_hi[0][0])[i] = 0; (&Sbt_lo[0][0])[i] = 0;
  }
  f32x4 Sfrag = {0.f, 0.f, 0.f, 0.f};

  const int kr0 = tid & 63, kd0 = (tid >> 6) << 3;
  const int kr1 = (tid + 512) & 63, kd1 = ((tid + 512) >> 6) << 3;
  const int ur = tid & 63, uc = tid >> 6;   // U0 staging: (ur, uc) and (ur, uc+8)

  // prefetch chunk 0
  us8 kpre0 = *(const us8*)&kbase[(size_t)kr0 * QKS + kd0];
  us8 kpre1 = *(const us8*)&kbase[(size_t)kr1 * QKS + kd1];
  u16 upre0 = uobase[(size_t)ur * DV + uc];
  u16 upre1 = uobase[(size_t)ur * DV + uc + 8];
  bf16x8 mpre[4];
#pragma unroll
  for (int kt = 0; kt < 4; ++kt)
    mpre[kt] = *(const bf16x8*)&Mbase[(size_t)(16 * wid + fr) * 128 + kt * 32 + fq * 8];
  bf16x8 qppre[4];
  bf16x8 qkpre0 = {}, qkpre1 = {};
  if (wid >= 4) {
    const u16* qp = Qpbase + (size_t)(m0w + fr) * DQH + fq * 8;
#pragma unroll
    for (int kt = 0; kt < 4; ++kt) qppre[kt] = *(const bf16x8*)&qp[kt * 32];
    const u16* qkp = QKbase + (size_t)(m0w + fr) * CH + fq * 8;
    qkpre0 = *(const bf16x8*)&qkp[0];
    qkpre1 = *(const bf16x8*)&qkp[32];
  }
  // commit chunk-0 K / U0 to LDS
#pragma unroll
  for (int j = 0; j < 8; ++j) Kt[kd0 + j][kr0] = kpre0.u[j];
#pragma unroll
  for (int j = 0; j < 8; ++j) Kt[kd1 + j][kr1] = kpre1.u[j];
  U0t[uc][ur] = upre0;
  U0t[uc + 8][ur] = upre1;
  __syncthreads();

  for (int ch = 0; ch < 64; ++ch) {
    const int c0 = ch * CH;
    // reg moves pre -> cur
    bf16x8 mcur[4];
#pragma unroll
    for (int kt = 0; kt < 4; ++kt) mcur[kt] = mpre[kt];
    bf16x8 qpc[4];
    bf16x8 qkc0 = qkpre0, qkc1 = qkpre1;
    if (wid >= 4) {
#pragma unroll
      for (int kt = 0; kt < 4; ++kt) qpc[kt] = qppre[kt];
    }
    // issue prefetches for ch+1
    if (ch + 1 < 64) {
      const int cn = c0 + CH;
      kpre0 = *(const us8*)&kbase[(size_t)(cn + kr0) * QKS + kd0];
      kpre1 = *(const us8*)&kbase[(size_t)(cn + kr1) * QKS + kd1];
      upre0 = uobase[(size_t)(cn + ur) * DV + uc];
      upre1 = uobase[(size_t)(cn + ur) * DV + uc + 8];
#pragma unroll
      for (int kt = 0; kt < 4; ++kt)
        mpre[kt] = *(const bf16x8*)&Mbase[(size_t)(ch + 1) * (128 * 128) +
                                          (size_t)(16 * wid + fr) * 128 + kt * 32 + fq * 8];
      if (wid >= 4) {
        const u16* qp = Qpbase + (size_t)(cn + m0w + fr) * DQH + fq * 8;
#pragma unroll
        for (int kt = 0; kt < 4; ++kt) qppre[kt] = *(const bf16x8*)&qp[kt * 32];
        const u16* qkp = QKbase + (size_t)(cn + m0w + fr) * CH + fq * 8;
        qkpre0 = *(const bf16x8*)&qkp[0];
        qkpre1 = *(const bf16x8*)&qkp[32];
      }
    }
    // Z = K^T · U0 (off critical path,独立 chain)
    f32x4 zacc = {0.f, 0.f, 0.f, 0.f};
    __builtin_amdgcn_s_setprio(1);
#pragma unroll
    for (int kt = 0; kt < 2; ++kt) {
      bf16x8 kf = *(const bf16x8*)&Kt[16 * wid + fr][kt * 32 + fq * 8];
      bf16x8 uf = *(const bf16x8*)&U0t[fr][kt * 32 + fq * 8];
      zacc = __builtin_amdgcn_mfma_f32_16x16x32_bf16(kf, uf, zacc, 0, 0, 0);
    }
    // chain: S + M·S (two independent 4-chains)
    f32x4 accA = Sfrag, accB = {0.f, 0.f, 0.f, 0.f};
#pragma unroll
    for (int kt = 0; kt < 2; ++kt) {
      bf16x8 sh = *(const bf16x8*)&Sbt_hi[fr][kt * 32 + fq * 8];
      bf16x8 sl = *(const bf16x8*)&Sbt_lo[fr][kt * 32 + fq * 8];
      accA = __builtin_amdgcn_mfma_f32_16x16x32_bf16(mcur[kt], sh, accA, 0, 0, 0);
      accA = __builtin_amdgcn_mfma_f32_16x16x32_bf16(mcur[kt], sl, accA, 0, 0, 0);
    }
#pragma unroll
    for (int kt = 2; kt < 4; ++kt) {
      bf16x8 sh = *(const bf16x8*)&Sbt_hi[fr][kt * 32 + fq * 8];
      bf16x8 sl = *(const bf16x8*)&Sbt_lo[fr][kt * 32 + fq * 8];
      accB = __builtin_amdgcn_mfma_f32_16x16x32_bf16(mcur[kt], sh, accB, 0, 0, 0);
      accB = __builtin_amdgcn_mfma_f32_16x16x32_bf16(mcur[kt], sl, accB, 0, 0, 0);
    }
    __builtin_amdgcn_s_setprio(0);
    // O path (waves 4-7): O = Q'·S_hi + QK·U0
    f32x4 oacc = {0.f, 0.f, 0.f, 0.f};
    if (wid >= 4) {
#pragma unroll
      for (int kt = 0; kt < 4; ++kt) {
        bf16x8 sh = *(const bf16x8*)&Sbt_hi[fr][kt * 32 + fq * 8];
        oacc = __builtin_amdgcn_mfma_f32_16x16x32_bf16(qpc[kt], sh, oacc, 0, 0, 0);
      }
      bf16x8 uf0 = *(const bf16x8*)&U0t[fr][fq * 8];
      bf16x8 uf1 = *(const bf16x8*)&U0t[fr][32 + fq * 8];
      oacc = __builtin_amdgcn_mfma_f32_16x16x32_bf16(qkc0, uf0, oacc, 0, 0, 0);
      oacc = __builtin_amdgcn_mfma_f32_16x16x32_bf16(qkc1, uf1, oacc, 0, 0, 0);
    }
    __syncthreads();   // all Sbt/Kt/U0t reads complete

    // publish S' = S + M·S + Z
    Sfrag[0] = accA[0] + accB[0] + zacc[0];
    Sfrag[1] = accA[1] + accB[1] + zacc[1];
    Sfrag[2] = accA[2] + accB[2] + zacc[2];
    Sfrag[3] = accA[3] + accB[3] + zacc[3];
    ushort4 shv, slv;
#pragma unroll
    for (int i = 0; i < 4; ++i) {
      float s = Sfrag[i];
      u16 hpart = f2b(s);
      ((u16*)&shv)[i] = hpart;
      ((u16*)&slv)[i] = f2b(s - b2f(hpart));
    }
    *(ushort4*)&Sbt_hi[fr][16 * wid + fq * 4] = shv;
    *(ushort4*)&Sbt_lo[fr][16 * wid + fq * 4] = slv;
    // O store (rows of current chunk; next-chunk U0 already prefetched)
    if (wid >= 4) {
      u16* op = uobase + (size_t)(c0 + m0w + fq * 4) * DV + fr;
      op[0] = f2b(oacc[0]);
      op[(size_t)DV] = f2b(oacc[1]);
      op[(size_t)2 * DV] = f2b(oacc[2]);
      op[(size_t)3 * DV] = f2b(oacc[3]);
    }
    // commit next-chunk K / U0 into LDS (reads finished at barrier above)
    if (ch + 1 < 64) {
#pragma unroll
      for (int j = 0; j < 8; ++j) Kt[kd0 + j][kr0] = kpre0.u[j];
#pragma unroll
      for (int j = 0; j < 8; ++j) Kt[kd1 + j][kr1] = kpre1.u[j];
      U0t[uc][ur] = upre0;
      U0t[uc + 8][ur] = upre1;
    }
    __syncthreads();   // publish + commits visible
  }
}

// ---- FUSED: blocks 0-255 scan2; 256-1279 Wg GEMM ----
__global__ __launch_bounds__(512) void scan2_wg_kernel(
    const u16* __restrict__ qk, const u16* __restrict__ Qp,
    const u16* __restrict__ QKb, const u16* __restrict__ Mb, u16* uo,
    const u16* __restrict__ A, const u16* __restrict__ BT, u16* __restrict__ C) {
  __shared__ alignas(16) u16 Kt[128][72];
  __shared__ alignas(16) u16 Sbt_hi[16][136];
  __shared__ alignas(16) u16 Sbt_lo[16][136];
  __shared__ alignas(16) u16 U0t[16][72];
  __shared__ u16 As[128 * 64];
  __shared__ u16 Bs[128 * 64];

  if (blockIdx.x < 256) {
    scan2_body(blockIdx.x, qk, Qp, QKb, Mb, uo, Kt, Sbt_hi, Sbt_lo, U0t);
    return;
  }
  const int tid = threadIdx.x;
  const int wid = tid >> 6, lane = tid & 63;
  const int wr = wid >> 2, wc = wid & 3;
  const int fr = lane & 15, fk = lane >> 4;
  const int nbx = DV >> 7;
  const int gbid = blockIdx.x - 256, nwg = 1024;
  const int swz = (gbid & 7) * (nwg >> 3) + (gbid >> 3);
  const int row0 = (swz / nbx) * 128, col0 = (swz % nbx) * 128;

  int sr[2], sk[2];
#pragma unroll
  for (int i = 0; i < 2; ++i) {
    int s = i * 8 + wid;
    int r = s * 8 + (lane >> 3);
    sr[i] = r;
    sk[i] = ((lane & 7) ^ (r & 7)) << 3;
  }

  f32x4 acc[4][2];
#pragma unroll
  for (int i = 0; i < 4; ++i)
#pragma unroll
    for (int j = 0; j < 2; ++j) acc[i][j] = {0.f, 0.f, 0.f, 0.f};

  for (int k0 = 0; k0 < Dm; k0 += 64) {
#pragma unroll
    for (int i = 0; i < 2; ++i) {
      const int s = i * 8 + wid;
      gld16(&A[(size_t)(row0 + sr[i]) * Dm + k0 + sk[i]], &As[s * 512]);
      gld16(&BT[(size_t)(col0 + sr[i]) * Dm + k0 + sk[i]], &Bs[s * 512]);
    }
    __syncthreads();
#pragma unroll
    for (int kt = 0; kt < 2; ++kt) {
      bf16x8 af[4], bf[2];
#pragma unroll
      for (int mi = 0; mi < 4; ++mi) {
        int row = wr * 64 + mi * 16 + fr;
        af[mi] = *(const bf16x8*)&As[row * 64 + (((kt * 4 + fk) ^ (fr & 7)) << 3)];
      }
#pragma unroll
      for (int ni = 0; ni < 2; ++ni) {
        int row = wc * 32 + ni * 16 + fr;
        bf[ni] = *(const bf16x8*)&Bs[row * 64 + (((kt * 4 + fk) ^ (fr & 7)) << 3)];
      }
#pragma unroll
      for (int mi = 0; mi < 4; ++mi)
#pragma unroll
        for (int ni = 0; ni < 2; ++ni)
          acc[mi][ni] = __builtin_amdgcn_mfma_f32_16x16x32_bf16(
              af[mi], bf[ni], acc[mi][ni], 0, 0, 0);
    }
    __syncthreads();
  }
#pragma unroll
  for (int mi = 0; mi < 4; ++mi)
#pragma unroll
    for (int ni = 0; ni < 2; ++ni) {
      int col = col0 + wc * 32 + ni * 16 + fr;
#pragma unroll
      for (int r = 0; r < 4; ++r) {
        int row = row0 + wr * 64 + mi * 16 + fk * 4 + r;
        C[(size_t)row * DV + col] = f2b(acc[mi][ni][r]);
      }
    }
}

// ---- OLD scan body (round-17 proven) for fallback tiers ----
__device__ __forceinline__ void scan_body(
    int sbid, const u16* __restrict__ qkp,
    const u16* __restrict__ Wb, const u16* __restrict__ QKb, u16* uo,
    u16 (*Kt)[72], u16 (*Sbt_hi)[136], u16 (*Sbt_lo)[136], u16 (*Ubt)[72]) {
  const int tid = threadIdx.x;
  const int wid = tid >> 6, lane = tid & 63;
  const int fr = lane & 15, fq = lane >> 4;
  const int m0w = 16 * (wid & 3);
  const int bh = sbid & 15, vblk = sbid >> 4;
  const int b = bh >> 2, hh = bh & 3;
  const u16* qbase = qkp + (size_t)b * Lseq * QKS + hh * DQH;
  const u16* kbase = qkp + (size_t)b * Lseq * QKS + 512 + hh * DQH;
  const u16* Wbase = Wb + (size_t)bh * Lseq * DQH;
  const u16* QKbase = QKb + (size_t)bh * Lseq * CH;
  u16* uobase = uo + (size_t)b * Lseq * DV + hh * DVH + vblk * 16;

  for (int i = tid; i < 16 * 136; i += 512) {
    (&Sbt_hi[0][0])[i] = 0; (&Sbt_lo[0][0])[i] = 0;
  }
  f32x4 Sfrag = {0.f, 0.f, 0.f, 0.f};

  const int kr0 = tid & 63, kd0 = (tid >> 6) << 3;
  const int kr1 = (tid + 512) & 63, kd1 = ((tid + 512) >> 6) << 3;

  us8 kpre0 = *(const us8*)&kbase[(size_t)kr0 * QKS + kd0];
  us8 kpre1 = *(const us8*)&kbase[(size_t)kr1 * QKS + kd1];
  bf16x8 fpre[4];
  bf16x8 qkpre0 = {}, qkpre1 = {};
  ushort4 u0pre = {};
  if (wid < 4) {
    const u16* wp = Wbase + (size_t)(m0w + fr) * DQH + fq * 8;
#pragma unroll
    for (int kt = 0; kt < 4; ++kt) fpre[kt] = *(const bf16x8*)&wp[kt * 32];
    const u16* up = uobase + (size_t)(m0w + fq * 4) * DV + fr;
    u0pre.x = up[0]; u0pre.y = up[(size_t)DV];
    u0pre.z = up[(size_t)2 * DV]; u0pre.w = up[(size_t)3 * DV];
  } else {
    const u16* qp = qbase + (size_t)(m0w + fr) * QKS + fq * 8;
#pragma unroll
    for (int kt = 0; kt < 4; ++kt) fpre[kt] = *(const bf16x8*)&qp[kt * 32];
    const u16* qkp2 = QKbase + (size_t)(m0w + fr) * CH + fq * 8;
    qkpre0 = *(const bf16x8*)&qkp2[0];
    qkpre1 = *(const bf16x8*)&qkp2[32];
  }
  __syncthreads();

  for (int c0 = 0; c0 < Lseq; c0 += CH) {
#pragma unroll
    for (int j = 0; j < 8; ++j) Kt[kd0 + j][kr0] = kpre0.u[j];
#pragma unroll
    for (int j = 0; j < 8; ++j) Kt[kd1 + j][kr1] = kpre1.u[j];

    bf16x8 fcur[4];
#pragma unroll
    for (int kt = 0; kt < 4; ++kt) fcur[kt] = fpre[kt];
    bf16x8 qkc0 = qkpre0, qkc1 = qkpre1;
    ushort4 u0c = u0pre;

    if (c0 + CH < Lseq) {
      const int cn = c0 + CH;
      kpre0 = *(const us8*)&kbase[(size_t)(cn + kr0) * QKS + kd0];
      kpre1 = *(const us8*)&kbase[(size_t)(cn + kr1) * QKS + kd1];
      if (wid < 4) {
        const u16* wp = Wbase + (size_t)(cn + m0w + fr) * DQH + fq * 8;
#pragma unroll
        for (int kt = 0; kt < 4; ++kt) fpre[kt] = *(const bf16x8*)&wp[kt * 32];
        const u16* up = uobase + (size_t)(cn + m0w + fq * 4) * DV + fr;
        u0pre.x = up[0]; u0pre.y = up[(size_t)DV];
        u0pre.z = up[(size_t)2 * DV]; u0pre.w = up[(size_t)3 * DV];
      } else {
        const u16* qp = qbase + (size_t)(cn + m0w + fr) * QKS + fq * 8;
#pragma unroll
        for (int kt = 0; kt < 4; ++kt) fpre[kt] = *(const bf16x8*)&qp[kt * 32];
        const u16* qkp2 = QKbase + (size_t)(cn + m0w + fr) * CH + fq * 8;
        qkpre0 = *(const bf16x8*)&qkp2[0];
        qkpre1 = *(const bf16x8*)&qkp2[32];
      }
    }

    f32x4 acc, accB;
    if (wid < 4) {
      acc[0] = b2f(u0c.x); acc[1] = b2f(u0c.y);
      acc[2] = b2f(u0c.z); acc[3] = b2f(u0c.w);
      accB = (f32x4){0.f, 0.f, 0.f, 0.f};
      __builtin_amdgcn_s_setprio(1);
#pragma unroll
      for (int kt = 0; kt < 2; ++kt) {
        bf16x8 sh = *(const bf16x8*)&Sbt_hi[fr][kt * 32 + fq * 8];
        bf16x8 sl = *(const bf16x8*)&Sbt_lo[fr][kt * 32 + fq * 8];
        acc = __builtin_amdgcn_mfma_f32_16x16x32_bf16(fcur[kt], sh, acc, 0, 0, 0);
        acc = __builtin_amdgcn_mfma_f32_16x16x32_bf16(fcur[kt], sl, acc, 0, 0, 0);
      }
#pragma unroll
      for (int kt = 2; kt < 4; ++kt) {
        bf16x8 sh = *(const bf16x8*)&Sbt_hi[fr][kt * 32 + fq * 8];
        bf16x8 sl = *(const bf16x8*)&Sbt_lo[fr][kt * 32 + fq * 8];
        accB = __builtin_amdgcn_mfma_f32_16x16x32_bf16(fcur[kt], sh, accB, 0, 0, 0);
        accB = __builtin_amdgcn_mfma_f32_16x16x32_bf16(fcur[kt], sl, accB, 0, 0, 0);
      }
      __builtin_amdgcn_s_setprio(0);
      ushort4 ub = {f2b(acc[0] + accB[0]), f2b(acc[1] + accB[1]),
                    f2b(acc[2] + accB[2]), f2b(acc[3] + accB[3])};
      *(ushort4*)&Ubt[fr][m0w + fq * 4] = ub;
    } else {
      acc = (f32x4){0.f, 0.f, 0.f, 0.f};
      accB = (f32x4){0.f, 0.f, 0.f, 0.f};
#pragma unroll
      for (int kt = 0; kt < 2; ++kt) {
        bf16x8 sh = *(const bf16x8*)&Sbt_hi[fr][kt * 32 + fq * 8];
        acc = __builtin_amdgcn_mfma_f32_16x16x32_bf16(fcur[kt], sh, acc, 0, 0, 0);
      }
#pragma unroll
      for (int kt = 2; kt < 4; ++kt) {
        bf16x8 sh = *(const bf16x8*)&Sbt_hi[fr][kt * 32 + fq * 8];
        accB = __builtin_amdgcn_mfma_f32_16x16x32_bf16(fcur[kt], sh, accB, 0, 0, 0);
      }
    }
    __syncthreads();

    if (wid >= 4) {
      bf16x8 uf0 = *(const bf16x8*)&Ubt[fr][fq * 8];
      bf16x8 uf1 = *(const bf16x8*)&Ubt[fr][32 + fq * 8];
      acc  = __builtin_amdgcn_mfma_f32_16x16x32_bf16(qkc0, uf0, acc, 0, 0, 0);
      accB = __builtin_amdgcn_mfma_f32_16x16x32_bf16(qkc1, uf1, accB, 0, 0, 0);
      u16* op = uobase + (size_t)(c0 + m0w + fq * 4) * DV + fr;
      op[0] = f2b(acc[0] + accB[0]);
      op[(size_t)DV] = f2b(acc[1] + accB[1]);
      op[(size_t)2 * DV] = f2b(acc[2] + accB[2]);
      op[(size_t)3 * DV] = f2b(acc[3] + accB[3]);
    }
    __builtin_amdgcn_s_setprio(1);
#pragma unroll
    for (int kt = 0; kt < 2; ++kt) {
      bf16x8 kf = *(const bf16x8*)&Kt[16 * wid + fr][kt * 32 + fq * 8];
      bf16x8 uf = *(const bf16x8*)&Ubt[fr][kt * 32 + fq * 8];
      Sfrag = __builtin_amdgcn_mfma_f32_16x16x32_bf16(kf, uf, Sfrag, 0, 0, 0);
    }
    __builtin_amdgcn_s_setprio(0);
    ushort4 shv, slv;
#pragma unroll
    for (int i = 0; i < 4; ++i) {
      float s = Sfrag[i];
      u16 hpart = f2b(s);
      ((u16*)&shv)[i] = hpart;
      ((u16*)&slv)[i] = f2b(s - b2f(hpart));
    }
    *(ushort4*)&Sbt_hi[fr][16 * wid + fq * 4] = shv;
    *(ushort4*)&Sbt_lo[fr][16 * wid + fq * 4] = slv;
    __syncthreads();
  }
}

__global__ __launch_bounds__(512) void delta_scan_kernel(
    const u16* __restrict__ qk, const u16* __restrict__ Wb,
    const u16* __restrict__ QKb, u16* uo) {
  __shared__ alignas(16) u16 Kt[128][72];
  __shared__ alignas(16) u16 Sbt_hi[16][136];
  __shared__ alignas(16) u16 Sbt_lo[16][136];
  __shared__ alignas(16) u16 Ubt[16][72];
  scan_body(blockIdx.x, qk, Wb, QKb, uo, Kt, Sbt_hi, Sbt_lo, Ubt);
}

__global__ __launch_bounds__(512) void scan_wg_kernel(
    const u16* __restrict__ qk, const u16* __restrict__ Wb,
    const u16* __restrict__ QKb, u16* uo,
    const u16* __restrict__ A, const u16* __restrict__ BT, u16* __restrict__ C) {
  __shared__ alignas(16) u16 Kt[128][72];
  __shared__ alignas(16) u16 Sbt_hi[16][136];
  __shared__ alignas(16) u16 Sbt_lo[16][136];
  __shared__ alignas(16) u16 Ubt[16][72];
  __shared__ u16 As[128 * 64];
  __shared__ u16 Bs[128 * 64];

  if (blockIdx.x < 256) {
    scan_body(blockIdx.x, qk, Wb, QKb, uo, Kt, Sbt_hi, Sbt_lo, Ubt);
    return;
  }
  const int tid = threadIdx.x;
  const int wid = tid >> 6, lane = tid & 63;
  const int wr = wid >> 2, wc = wid & 3;
  const int fr = lane & 15, fk = lane >> 4;
  const int nbx = DV >> 7;
  const int gbid = blockIdx.x - 256, nwg = 1024;
  const int swz = (gbid & 7) * (nwg >> 3) + (gbid >> 3);
  const int row0 = (swz / nbx) * 128, col0 = (swz % nbx) * 128;

  int sr[2], sk[2];
#pragma unroll
  for (int i = 0; i < 2; ++i) {
    int s = i * 8 + wid;
    int r = s * 8 + (lane >> 3);
    sr[i] = r;
    sk[i] = ((lane & 7) ^ (r & 7)) << 3;
  }

  f32x4 acc[4][2];
#pragma unroll
  for (int i = 0; i < 4; ++i)
#pragma unroll
    for (int j = 0; j < 2; ++j) acc[i][j] = {0.f, 0.f, 0.f, 0.f};

  for (int k0 = 0; k0 < Dm; k0 += 64) {
#pragma unroll
    for (int i = 0; i < 2; ++i) {
      const int s = i * 8 + wid;
      gld16(&A[(size_t)(row0 + sr[i]) * Dm + k0 + sk[i]], &As[s * 512]);
      gld16(&BT[(size_t)(col0 + sr[i]) * Dm + k0 + sk[i]], &Bs[s * 512]);
    }
    __syncthreads();
#pragma unroll
    for (int kt = 0; kt < 2; ++kt) {
      bf16x8 af[4], bf[2];
#pragma unroll
      for (int mi = 0; mi < 4; ++mi) {
        int row = wr * 64 + mi * 16 + fr;
        af[mi] = *(const bf16x8*)&As[row * 64 + (((kt * 4 + fk) ^ (fr & 7)) << 3)];
      }
#pragma unroll
      for (int ni = 0; ni < 2; ++ni) {
        int row = wc * 32 + ni * 16 + fr;
        bf[ni] = *(const bf16x8*)&Bs[row * 64 + (((kt * 4 + fk) ^ (fr & 7)) << 3)];
      }
#pragma unroll
      for (int mi = 0; mi < 4; ++mi)
#pragma unroll
        for (int ni = 0; ni < 2; ++ni)
          acc[mi][ni] = __builtin_amdgcn_mfma_f32_16x16x32_bf16(
              af[mi], bf[ni], acc[mi][ni], 0, 0, 0);
    }
    __syncthreads();
  }
#pragma unroll
  for (int mi = 0; mi < 4; ++mi)
#pragma unroll
    for (int ni = 0; ni < 2; ++ni) {
      int col = col0 + wc * 32 + ni * 16 + fr;
#pragma unroll
      for (int r = 0; r < 4; ++r) {
        int row = row0 + wr * 64 + mi * 16 + fk * 4 + r;
        C[(size_t)row * DV + col] = f2b(acc[mi][ni][r]);
      }
    }
}

// ---- 6. gate ----
__global__ __launch_bounds__(256) void gate_kernel(
    const u16* og, const u16* __restrict__ g,
    const float* __restrict__ nw, u16* out) {
  int idx = blockIdx.x * 4 + (threadIdx.x >> 6), lane = threadIdx.x & 63;
  size_t base = (size_t)(idx >> 2) * DV + (size_t)(idx & 3) * DVH + (size_t)lane * 4;
  ushort4 o4 = *(const ushort4*)&og[base];
  float ox = b2f(o4.x), oy = b2f(o4.y), oz = b2f(o4.z), ow = b2f(o4.w);
  float ss = ox * ox + oy * oy + oz * oz + ow * ow;
#pragma unroll
  for (int off = 32; off; off >>= 1) ss += __shfl_xor(ss, off);
  float r = 1.f / sqrtf(ss * (1.f / DVH) + 1e-5f);
  ushort4 g4 = *(const ushort4*)&g[base];
  float gx = b2f(g4.x), gy = b2f(g4.y), gz = b2f(g4.z), gw = b2f(g4.w);
  float4 wv = *(const float4*)&nw[lane * 4];
  ushort4 res;
  res.x = f2b(ox * r * wv.x * (gx * sig_(gx)));
  res.y = f2b(oy * r * wv.y * (gy * sig_(gy)));
  res.z = f2b(oz * r * wv.z * (gz * sig_(gz)));
  res.w = f2b(ow * r * wv.w * (gw * sig_(gw)));
  *(ushort4*)&out[base] = res;
}

__global__ __launch_bounds__(256) void gemm_bf16_kernel(
    const u16* __restrict__ A, const u16* __restrict__ BT, void* __restrict__ Cv,
    int M, int N, int K) {
  __shared__ u16 As[128 * 64];
  __shared__ u16 Bs[128 * 64];
  gemm_body<0>(A, BT, Cv, M, N, K, blockIdx.x, gridDim.x, As, Bs);
}

// ---- host ----
extern "C" void kernel_launch(void* const* d_in, const int* in_sizes, int n_in,
                              void* d_out, int out_size, void* d_ws, size_t ws_size,
                              hipStream_t stream) {
  (void)in_sizes; (void)n_in; (void)out_size;
  const float* x  = (const float*)d_in[0];
  const float* cw = (const float*)d_in[1];
  const float* Wq = (const float*)d_in[2];
  const float* Wk = (const float*)d_in[3];
  const float* Wv = (const float*)d_in[4];
  const float* Wb = (const float*)d_in[5];
  const float* Wg = (const float*)d_in[6];
  const float* nw = (const float*)d_in[7];
  const float* Wo = (const float*)d_in[8];
  float* out = (float*)d_out;   // f32 output

  u16* hb  = (u16*)d_ws;                       // ROWS*Dm
  u16* qkb = hb + (size_t)ROWS * Dm;           // ROWS*QKS (q | k)
  u16* vb  = qkb + (size_t)ROWS * QKS;         // ROWS*DV (v -> U0 -> O)
  float* bbuf = (float*)(vb + (size_t)ROWS * DV);
  u16* Wbuf  = (u16*)(bbuf + (size_t)ROWS * H);     // Wneg, then Q' (mk overwrites)
  u16* QKbuf = Wbuf + (size_t)16 * Lseq * DQH;
  u16* wq16 = QKbuf + (size_t)16 * Lseq * CH;
  u16* wk16 = wq16 + (size_t)Dm * DK;
  u16* wv16 = wk16 + (size_t)Dm * DK;
  u16* wg16 = wv16 + (size_t)Dm * DV;
  u16* wo16 = wg16 + (size_t)Dm * DV;
  u16* gb2  = wo16 + (size_t)DV * Dm;               // g buffer (fused paths)
  u16* Mbuf = gb2 + (size_t)ROWS * DV;              // 16*64*128*128 bf16
  u16* gb   = qkb;                                  // aliased g (unfused fallback)

  const size_t need = (size_t)ROWS * (Dm + QKS + DV) * 2 + (size_t)ROWS * H * 4
                    + (size_t)16 * Lseq * (DQH + CH) * 2
                    + ((size_t)Dm * (DK * 2 + DV * 3)) * 2;
  const size_t need2 = need + (size_t)ROWS * DV * 2;
  const size_t need3 = need2 + (size_t)16 * 64 * 128 * 128 * 2;
  if (ws_size < need) {
    ws_sentinel_kernel<<<1, 1, 0, stream>>>(out, (float)ws_size);
    return;
  }

  prologue_kernel<<<10240, 256, 0, stream>>>(x, cw, hb, Wq, Wk, Wv, Wg, Wo,
                                             wq16, wk16, wv16, wg16, wo16);
  proj_kernel<<<6144, 256, 0, stream>>>(hb, wq16, wv16, Wb, qkb, vb, bbuf);
  delta_prep_kernel<<<1024, 256, 0, stream>>>(qkb, vb, bbuf, Wbuf, QKbuf);

  if (ws_size >= need3) {
    // linearized scan: precompute M = K^T·Wneg, Q' = Q + QK·Wneg
    mk_kernel<<<1024, 256, 0, stream>>>(qkb, Wbuf, QKbuf, Mbuf);
    scan2_wg_kernel<<<1280, 512, 0, stream>>>(qkb, Wbuf, QKbuf, Mbuf, vb,
                                              hb, wg16, gb2);
    gate_kernel<<<ROWS * H / 4, 256, 0, stream>>>(vb, gb2, nw, vb);
  } else if (ws_size >= need2) {
    scan_wg_kernel<<<1280, 512, 0, stream>>>(qkb, Wbuf, QKbuf, vb, hb, wg16, gb2);
    gate_kernel<<<ROWS * H / 4, 256, 0, stream>>>(vb, gb2, nw, vb);
  } else {
    delta_scan_kernel<<<256, 512, 0, stream>>>(qkb, Wbuf, QKbuf, vb);
    gemm_bf16_kernel<<<(DV / 128) * (ROWS / 128), 256, 0, stream>>>(hb, wg16, gb, ROWS, DV, Dm);
    gate_kernel<<<ROWS * H / 4, 256, 0, stream>>>(vb, gb, nw, vb);
  }

  gemm_mfma_kernel<<<(Dm / 128) * (ROWS / 128), 256, 0, stream>>>(vb, wo16, out, ROWS, Dm, DV);
}

// Round 22
// 465.559 us; speedup vs baseline: 1.2500x; 1.2500x over previous
//
#include <hip/hip_runtime.h>
#include <math.h>

constexpr int Lseq = 4096, Dm = 1024, H = 4, DK = 512, DV = 1024;
constexpr int DQH = 128, DVH = 256, CH = 64, ROWS = 4 * 4096;
constexpr int QKS = 1024;   // combined q|k row stride

typedef unsigned short u16;
struct alignas(16) us8 { u16 u[8]; };
typedef __attribute__((ext_vector_type(8))) short bf16x8;
typedef __attribute__((ext_vector_type(4))) float f32x4;

__device__ __forceinline__ float sig_(float x) { return 1.f / (1.f + expf(-x)); }
__device__ __forceinline__ float b2f(u16 u) {
  union { float f; unsigned v; } x; x.v = (unsigned)u << 16; return x.f;
}
__device__ __forceinline__ u16 f2b(float f) {   // round-to-nearest-even
  union { float f; unsigned v; } x; x.f = f;
  unsigned r = x.v + 0x7fffu + ((x.v >> 16) & 1u);
  return (u16)(r >> 16);
}
__device__ __forceinline__ void gld16(const u16* g, u16* l) {
  __builtin_amdgcn_global_load_lds(
      (const __attribute__((address_space(1))) void*)g,
      (__attribute__((address_space(3))) void*)l, 16, 0, 0);
}

__global__ void ws_sentinel_kernel(float* out, float v) { out[0] = v; }

// ---- 1. PROLOGUE: conv+silu (blocks 0..8191) + weight cvt/T (blocks 8192..10239) ----
__global__ __launch_bounds__(256) void prologue_kernel(
    const float* __restrict__ x, const float* __restrict__ w, u16* __restrict__ h,
    const float* __restrict__ Wq, const float* __restrict__ Wk,
    const float* __restrict__ Wv, const float* __restrict__ Wg,
    const float* __restrict__ Wo,
    u16* wq16, u16* wk16, u16* wv16, u16* wg16, u16* wo16) {
  __shared__ u16 T[32][66];
  const int t = threadIdx.x;
  if (blockIdx.x < 8192) {   // conv + silu, 8 d-elems/thread
    int idx = blockIdx.x * 256 + t;
    int d8 = (idx & 127) << 3;
    int row = idx >> 7;
    int l = row & (Lseq - 1), b = row >> 12;
    const float* xb = x + ((size_t)b << 22);
    float4 wv_[8];
#pragma unroll
    for (int j = 0; j < 2; ++j) {
      wv_[j * 4 + 0] = *(const float4*)&w[d8 * 4 + j * 16 + 0];
      wv_[j * 4 + 1] = *(const float4*)&w[d8 * 4 + j * 16 + 4];
      wv_[j * 4 + 2] = *(const float4*)&w[d8 * 4 + j * 16 + 8];
      wv_[j * 4 + 3] = *(const float4*)&w[d8 * 4 + j * 16 + 12];
    }
    float acc[8] = {0, 0, 0, 0, 0, 0, 0, 0};
#pragma unroll
    for (int i = 0; i < 4; ++i) {
      int li = l - 3 + i;
      if (li >= 0) {
        float4 x0 = *(const float4*)&xb[((size_t)li << 10) + d8];
        float4 x1 = *(const float4*)&xb[((size_t)li << 10) + d8 + 4];
        acc[0] = fmaf(((const float*)&wv_[0])[i], x0.x, acc[0]);
        acc[1] = fmaf(((const float*)&wv_[1])[i], x0.y, acc[1]);
        acc[2] = fmaf(((const float*)&wv_[2])[i], x0.z, acc[2]);
        acc[3] = fmaf(((const float*)&wv_[3])[i], x0.w, acc[3]);
        acc[4] = fmaf(((const float*)&wv_[4])[i], x1.x, acc[4]);
        acc[5] = fmaf(((const float*)&wv_[5])[i], x1.y, acc[5]);
        acc[6] = fmaf(((const float*)&wv_[6])[i], x1.z, acc[6]);
        acc[7] = fmaf(((const float*)&wv_[7])[i], x1.w, acc[7]);
      }
    }
    us8 o;
#pragma unroll
    for (int j = 0; j < 8; ++j) o.u[j] = f2b(acc[j] * sig_(acc[j]));
    *(us8*)&h[(size_t)row * Dm + d8] = o;
    return;
  }
  // weight convert + transpose
  int bid = blockIdx.x - 8192;
  const float* in; u16* out; int N, K, b0;
  if (bid < 256)       { in = Wq; out = wq16; N = DK; K = Dm; b0 = bid; }
  else if (bid < 512)  { in = Wk; out = wk16; N = DK; K = Dm; b0 = bid - 256; }
  else if (bid < 1024) { in = Wv; out = wv16; N = DV; K = Dm; b0 = bid - 512; }
  else if (bid < 1536) { in = Wg; out = wg16; N = DV; K = Dm; b0 = bid - 1024; }
  else                 { in = Wo; out = wo16; N = Dm; K = DV; b0 = bid - 1536; }
  const int nbx = N / 64;
  const int k0 = (b0 / nbx) * 32, n0 = (b0 % nbx) * 64;
#pragma unroll
  for (int i = 0; i < 8; ++i) {
    int idx = t + i * 256;
    int kk = idx >> 6, nn = idx & 63;
    T[kk][nn] = f2b(in[(size_t)(k0 + kk) * N + n0 + nn]);
  }
  __syncthreads();
#pragma unroll
  for (int i = 0; i < 8; ++i) {
    int idx = t + i * 256;
    int kk = idx & 31, nn = idx >> 5;
    out[(size_t)(n0 + nn) * K + k0 + kk] = T[kk][nn];
  }
}

// ---- GEMM body (BK=64 + swizzle, round-16 proven), 256 thr ----
template <int MODE>
__device__ __forceinline__ void gemm_body(
    const u16* __restrict__ A, const u16* __restrict__ BT, void* __restrict__ Cv,
    int M, int N, int K, int bid, int nwg, u16* As, u16* Bs) {
  const int tid = threadIdx.x;
  const int wid = tid >> 6, lane = tid & 63;
  const int wr = wid >> 1, wc = wid & 1;
  const int fr = lane & 15, fk = lane >> 4;
  const int nbx = N >> 7;
  const int swz = (bid & 7) * (nwg >> 3) + (bid >> 3);   // T1: nwg % 8 == 0
  const int row0 = (swz / nbx) * 128, col0 = (swz % nbx) * 128;

  int sr[4], sk[4];
#pragma unroll
  for (int i = 0; i < 4; ++i) {
    int s = i * 4 + wid;
    int r = s * 8 + (lane >> 3);
    sr[i] = r;
    sk[i] = ((lane & 7) ^ (r & 7)) << 3;
  }

  f32x4 acc[4][4];
#pragma unroll
  for (int i = 0; i < 4; ++i)
#pragma unroll
    for (int j = 0; j < 4; ++j) acc[i][j] = {0.f, 0.f, 0.f, 0.f};

  for (int k0 = 0; k0 < K; k0 += 64) {
#pragma unroll
    for (int i = 0; i < 4; ++i) {
      const int s = i * 4 + wid;
      gld16(&A[(size_t)(row0 + sr[i]) * K + k0 + sk[i]], &As[s * 512]);
      gld16(&BT[(size_t)(col0 + sr[i]) * K + k0 + sk[i]], &Bs[s * 512]);
    }
    __syncthreads();
#pragma unroll
    for (int kt = 0; kt < 2; ++kt) {
      bf16x8 af[4], bf[4];
#pragma unroll
      for (int mi = 0; mi < 4; ++mi) {
        int row = wr * 64 + mi * 16 + fr;
        af[mi] = *(const bf16x8*)&As[row * 64 + (((kt * 4 + fk) ^ (fr & 7)) << 3)];
      }
#pragma unroll
      for (int ni = 0; ni < 4; ++ni) {
        int row = wc * 64 + ni * 16 + fr;
        bf[ni] = *(const bf16x8*)&Bs[row * 64 + (((kt * 4 + fk) ^ (fr & 7)) << 3)];
      }
#pragma unroll
      for (int mi = 0; mi < 4; ++mi)
#pragma unroll
        for (int ni = 0; ni < 4; ++ni)
          acc[mi][ni] = __builtin_amdgcn_mfma_f32_16x16x32_bf16(
              af[mi], bf[ni], acc[mi][ni], 0, 0, 0);
    }
    __syncthreads();
  }

  if (MODE == 2) {
    __shared__ float ssh[2][128];
#pragma unroll
    for (int mi = 0; mi < 4; ++mi)
#pragma unroll
      for (int r = 0; r < 4; ++r) {
        float p = 0.f;
#pragma unroll
        for (int ni = 0; ni < 4; ++ni) p += acc[mi][ni][r] * acc[mi][ni][r];
        p += __shfl_xor(p, 1); p += __shfl_xor(p, 2);
        p += __shfl_xor(p, 4); p += __shfl_xor(p, 8);
        if (fr == 0) ssh[wc][wr * 64 + mi * 16 + fk * 4 + r] = p;
      }
    __syncthreads();
#pragma unroll
    for (int mi = 0; mi < 4; ++mi)
#pragma unroll
      for (int r = 0; r < 4; ++r) {
        int ridx = wr * 64 + mi * 16 + fk * 4 + r;
        float sc = 1.f / fmaxf(sqrtf(ssh[0][ridx] + ssh[1][ridx]), 1e-12f);
#pragma unroll
        for (int ni = 0; ni < 4; ++ni) acc[mi][ni][r] *= sc;
      }
  }

#pragma unroll
  for (int mi = 0; mi < 4; ++mi)
#pragma unroll
    for (int ni = 0; ni < 4; ++ni) {
      int col = col0 + wc * 64 + ni * 16 + fr;
#pragma unroll
      for (int r = 0; r < 4; ++r) {
        int row = row0 + wr * 64 + mi * 16 + fk * 4 + r;
        if (MODE == 1) ((float*)Cv)[(size_t)row * N + col] = acc[mi][ni][r];
        else           ((u16*)Cv)[(size_t)row * N + col] = f2b(acc[mi][ni][r]);
      }
    }
}

__global__ __launch_bounds__(256) void gemm_mfma_kernel(
    const u16* __restrict__ A, const u16* __restrict__ BT, void* __restrict__ Cv,
    int M, int N, int K) {
  __shared__ u16 As[128 * 64];
  __shared__ u16 Bs[128 * 64];
  gemm_body<1>(A, BT, Cv, M, N, K, blockIdx.x, gridDim.x, As, Bs);
}

// ---- 2. PROJECTIONS mega-kernel ----
__global__ __launch_bounds__(256) void proj_kernel(
    const u16* __restrict__ hb, const u16* __restrict__ wqk16,
    const u16* __restrict__ wv16, const float* __restrict__ Wb,
    u16* __restrict__ qk, u16* __restrict__ vb, float* __restrict__ beta) {
  __shared__ u16 As[128 * 64];
  __shared__ u16 Bs[128 * 64];
  const int bid = blockIdx.x;
  if (bid < 1024) {
    gemm_body<2>(hb, wqk16, qk, ROWS, QKS, Dm, bid, 1024, As, Bs);
    return;
  }
  if (bid < 2048) {
    gemm_body<0>(hb, wv16, vb, ROWS, DV, Dm, bid - 1024, 1024, As, Bs);
    return;
  }
  int row = (bid - 2048) * 4 + (threadIdx.x >> 6), lane = threadIdx.x & 63;
  const u16* hrow = hb + (size_t)row * Dm;
  float a0 = 0, a1 = 0, a2 = 0, a3 = 0;
  for (int k0 = 0; k0 < Dm; k0 += 64) {
    float hv = b2f(hrow[k0 + lane]);
    float4 wv = *(const float4*)&Wb[(size_t)(k0 + lane) * 4];
    a0 = fmaf(hv, wv.x, a0); a1 = fmaf(hv, wv.y, a1);
    a2 = fmaf(hv, wv.z, a2); a3 = fmaf(hv, wv.w, a3);
  }
#pragma unroll
  for (int off = 32; off; off >>= 1) {
    a0 += __shfl_down(a0, off); a1 += __shfl_down(a1, off);
    a2 += __shfl_down(a2, off); a3 += __shfl_down(a3, off);
  }
  if (lane == 0) {
    int b = row >> 12, l = row & (Lseq - 1);
    beta[((size_t)(b * H + 0)) * Lseq + l] = sig_(a0);
    beta[((size_t)(b * H + 1)) * Lseq + l] = sig_(a1);
    beta[((size_t)(b * H + 2)) * Lseq + l] = sig_(a2);
    beta[((size_t)(b * H + 3)) * Lseq + l] = sig_(a3);
  }
}

// ---- 5a. delta prep v2 (round-18 proven) ----
__global__ __launch_bounds__(256) void delta_prep_kernel(
    const u16* __restrict__ qk, u16* v, const float* __restrict__ beta,
    u16* __restrict__ Wout, u16* __restrict__ QKout) {
  __shared__ alignas(16) char lds0[18432];
  __shared__ alignas(16) char lds1[18432];
  __shared__ float Bc[64];
  float (*Am)[68] = (float(*)[68])lds0;
  float (*R)[68]  = (float(*)[68])lds1;
  u16 (*Th)[72]  = (u16(*)[72])lds0;
  u16 (*Tl)[72]  = (u16(*)[72])(lds0 + 9216);
  u16 (*XTh)[72] = (u16(*)[72])lds1;
  u16 (*XTl)[72] = (u16(*)[72])(lds1 + 9216);

  const int tid = threadIdx.x;
  const int wid = tid >> 6, lane = tid & 63;
  const int fr = lane & 15, fq = lane >> 4;
  const int bh = blockIdx.x >> 6, ch = blockIdx.x & 63;
  const int b = bh >> 2, hh = bh & 3;
  const int c0 = ch * CH;
  const u16* qbase = qk + (size_t)b * Lseq * QKS + hh * DQH;
  const u16* kbase = qk + (size_t)b * Lseq * QKS + 512 + hh * DQH;
  u16*       vbase = v + (size_t)b * Lseq * DV + hh * DVH;
  const float* bbase = beta + (size_t)bh * Lseq;
  u16* Wrow  = Wout  + ((size_t)bh * Lseq + c0) * DQH;
  u16* QKrow = QKout + ((size_t)bh * Lseq + c0) * CH;

  if (tid < 64) Bc[tid] = bbase[c0 + tid];
  for (int idx = tid; idx < 64 * 64; idx += 256) {
    int r = idx >> 6, c = idx & 63;
    R[r][c] = (r == c) ? 1.f : 0.f;
  }
  __syncthreads();

  {
    const int m0 = wid * 16;
    f32x4 accG[4], accQ[4];
#pragma unroll
    for (int ni = 0; ni < 4; ++ni) {
      accG[ni] = {0.f, 0.f, 0.f, 0.f};
      accQ[ni] = {0.f, 0.f, 0.f, 0.f};
    }
#pragma unroll
    for (int kt = 0; kt < 4; ++kt) {
      bf16x8 afk = *(const bf16x8*)&kbase[(size_t)(c0 + m0 + fr) * QKS + kt * 32 + fq * 8];
      bf16x8 afq = *(const bf16x8*)&qbase[(size_t)(c0 + m0 + fr) * QKS + kt * 32 + fq * 8];
#pragma unroll
      for (int ni = 0; ni < 4; ++ni) {
        bf16x8 bfk = *(const bf16x8*)&kbase[(size_t)(c0 + ni * 16 + fr) * QKS + kt * 32 + fq * 8];
        accG[ni] = __builtin_amdgcn_mfma_f32_16x16x32_bf16(afk, bfk, accG[ni], 0, 0, 0);
        accQ[ni] = __builtin_amdgcn_mfma_f32_16x16x32_bf16(afq, bfk, accQ[ni], 0, 0, 0);
      }
    }
#pragma unroll
    for (int ni = 0; ni < 4; ++ni)
#pragma unroll
      for (int i = 0; i < 4; ++i) {
        int row = m0 + fq * 4 + i, col = ni * 16 + fr;
        float br = Bc[row];
        Am[row][col] = (col < row) ? br * accG[ni][i] : 0.f;
        QKrow[(size_t)row * CH + col] = f2b((col <= row) ? accQ[ni][i] : 0.f);
      }
  }
  __syncthreads();

  for (int rb = 0; rb < 4; ++rb) {
    if (rb > 0) {
      const int c = tid & 63, g = tid >> 6;
      const int R0 = rb * 16, row = R0 + g * 4;
      float s0 = 0, s1 = 0, s2 = 0, s3 = 0;
      for (int m = 0; m < R0; ++m) {
        float uv = R[m][c];
        s0 = fmaf(Am[row + 0][m], uv, s0);
        s1 = fmaf(Am[row + 1][m], uv, s1);
        s2 = fmaf(Am[row + 2][m], uv, s2);
        s3 = fmaf(Am[row + 3][m], uv, s3);
      }
      R[row + 0][c] -= s0; R[row + 1][c] -= s1;
      R[row + 2][c] -= s2; R[row + 3][c] -= s3;
    }
    __syncthreads();
    if (tid < 64) {
      const int c = tid;
      for (int i = 1; i < 16; ++i) {
        const int row = rb * 16 + i;
        float s = R[row][c];
        for (int m = 0; m < i; ++m)
          s = fmaf(-Am[row][rb * 16 + m], R[rb * 16 + m][c], s);
        R[row][c] = s;
      }
    }
    __syncthreads();
  }

  for (int idx = tid; idx < 64 * 64; idx += 256) {
    int r = idx >> 6, c = idx & 63;
    float tv = R[r][c];
    u16 hh2 = f2b(tv);
    Th[r][c] = hh2;
    Tl[r][c] = f2b(tv - b2f(hh2));
  }
  __syncthreads();

  for (int p = 0; p < 6; ++p) {
    const int off = (p < 2) ? p * 64 : (p - 2) * 64;
    for (int idx = tid; idx < 64 * 64; idx += 256) {
      int d = idx & 63, m = idx >> 6;
      float xv;
      if (p < 2) xv = Bc[m] * b2f(kbase[(size_t)(c0 + m) * QKS + off + d]);
      else       xv = Bc[m] * b2f(vbase[(size_t)(c0 + m) * DV + off + d]);
      u16 hh2 = f2b(xv);
      XTh[d][m] = hh2;
      XTl[d][m] = f2b(xv - b2f(hh2));
    }
    __syncthreads();
    f32x4 acc[4];
#pragma unroll
    for (int tn = 0; tn < 4; ++tn) acc[tn] = {0.f, 0.f, 0.f, 0.f};
#pragma unroll
    for (int kt = 0; kt < 2; ++kt) {
      bf16x8 ah = *(const bf16x8*)&Th[wid * 16 + fr][kt * 32 + fq * 8];
      bf16x8 al = *(const bf16x8*)&Tl[wid * 16 + fr][kt * 32 + fq * 8];
#pragma unroll
      for (int tn = 0; tn < 4; ++tn) {
        bf16x8 xh = *(const bf16x8*)&XTh[tn * 16 + fr][kt * 32 + fq * 8];
        bf16x8 xl = *(const bf16x8*)&XTl[tn * 16 + fr][kt * 32 + fq * 8];
        acc[tn] = __builtin_amdgcn_mfma_f32_16x16x32_bf16(ah, xh, acc[tn], 0, 0, 0);
        acc[tn] = __builtin_amdgcn_mfma_f32_16x16x32_bf16(ah, xl, acc[tn], 0, 0, 0);
        acc[tn] = __builtin_amdgcn_mfma_f32_16x16x32_bf16(al, xh, acc[tn], 0, 0, 0);
      }
    }
#pragma unroll
    for (int tn = 0; tn < 4; ++tn)
#pragma unroll
      for (int i = 0; i < 4; ++i) {
        int row = wid * 16 + fq * 4 + i, col = tn * 16 + fr;
        if (p < 2) Wrow[(size_t)row * DQH + off + col] = f2b(-acc[tn][i]);
        else       vbase[(size_t)(c0 + row) * DV + off + col] = f2b(acc[tn][i]);
      }
    __syncthreads();
  }
}

// ---- scan body (round-17/18 proven; q/k from combined qk, stride QKS) ----
__device__ __forceinline__ void scan_body(
    int sbid, const u16* __restrict__ qkp,
    const u16* __restrict__ Wb, const u16* __restrict__ QKb, u16* uo,
    u16 (*Kt)[72], u16 (*Sbt_hi)[136], u16 (*Sbt_lo)[136], u16 (*Ubt)[72]) {
  const int tid = threadIdx.x;
  const int wid = tid >> 6, lane = tid & 63;
  const int fr = lane & 15, fq = lane >> 4;
  const int m0w = 16 * (wid & 3);
  const int bh = sbid & 15, vblk = sbid >> 4;   // XCD-local bh
  const int b = bh >> 2, hh = bh & 3;
  const u16* qbase = qkp + (size_t)b * Lseq * QKS + hh * DQH;
  const u16* kbase = qkp + (size_t)b * Lseq * QKS + 512 + hh * DQH;
  const u16* Wbase = Wb + (size_t)bh * Lseq * DQH;
  const u16* QKbase = QKb + (size_t)bh * Lseq * CH;
  u16* uobase = uo + (size_t)b * Lseq * DV + hh * DVH + vblk * 16;

  for (int i = tid; i < 16 * 136; i += 512) {
    (&Sbt_hi[0][0])[i] = 0; (&Sbt_lo[0][0])[i] = 0;
  }
  f32x4 Sfrag = {0.f, 0.f, 0.f, 0.f};

  const int kr0 = tid & 63, kd0 = (tid >> 6) << 3;
  const int kr1 = (tid + 512) & 63, kd1 = ((tid + 512) >> 6) << 3;

  us8 kpre0 = *(const us8*)&kbase[(size_t)kr0 * QKS + kd0];
  us8 kpre1 = *(const us8*)&kbase[(size_t)kr1 * QKS + kd1];
  bf16x8 fpre[4];
  bf16x8 qkpre0 = {}, qkpre1 = {};
  ushort4 u0pre = {};
  if (wid < 4) {
    const u16* wp = Wbase + (size_t)(m0w + fr) * DQH + fq * 8;
#pragma unroll
    for (int kt = 0; kt < 4; ++kt) fpre[kt] = *(const bf16x8*)&wp[kt * 32];
    const u16* up = uobase + (size_t)(m0w + fq * 4) * DV + fr;
    u0pre.x = up[0]; u0pre.y = up[(size_t)DV];
    u0pre.z = up[(size_t)2 * DV]; u0pre.w = up[(size_t)3 * DV];
  } else {
    const u16* qp = qbase + (size_t)(m0w + fr) * QKS + fq * 8;
#pragma unroll
    for (int kt = 0; kt < 4; ++kt) fpre[kt] = *(const bf16x8*)&qp[kt * 32];
    const u16* qkp2 = QKbase + (size_t)(m0w + fr) * CH + fq * 8;
    qkpre0 = *(const bf16x8*)&qkp2[0];
    qkpre1 = *(const bf16x8*)&qkp2[32];
  }
  __syncthreads();

  for (int c0 = 0; c0 < Lseq; c0 += CH) {
#pragma unroll
    for (int j = 0; j < 8; ++j) Kt[kd0 + j][kr0] = kpre0.u[j];
#pragma unroll
    for (int j = 0; j < 8; ++j) Kt[kd1 + j][kr1] = kpre1.u[j];

    bf16x8 fcur[4];
#pragma unroll
    for (int kt = 0; kt < 4; ++kt) fcur[kt] = fpre[kt];
    bf16x8 qkc0 = qkpre0, qkc1 = qkpre1;
    ushort4 u0c = u0pre;

    if (c0 + CH < Lseq) {
      const int cn = c0 + CH;
      kpre0 = *(const us8*)&kbase[(size_t)(cn + kr0) * QKS + kd0];
      kpre1 = *(const us8*)&kbase[(size_t)(cn + kr1) * QKS + kd1];
      if (wid < 4) {
        const u16* wp = Wbase + (size_t)(cn + m0w + fr) * DQH + fq * 8;
#pragma unroll
        for (int kt = 0; kt < 4; ++kt) fpre[kt] = *(const bf16x8*)&wp[kt * 32];
        const u16* up = uobase + (size_t)(cn + m0w + fq * 4) * DV + fr;
        u0pre.x = up[0]; u0pre.y = up[(size_t)DV];
        u0pre.z = up[(size_t)2 * DV]; u0pre.w = up[(size_t)3 * DV];
      } else {
        const u16* qp = qbase + (size_t)(cn + m0w + fr) * QKS + fq * 8;
#pragma unroll
        for (int kt = 0; kt < 4; ++kt) fpre[kt] = *(const bf16x8*)&qp[kt * 32];
        const u16* qkp2 = QKbase + (size_t)(cn + m0w + fr) * CH + fq * 8;
        qkpre0 = *(const bf16x8*)&qkp2[0];
        qkpre1 = *(const bf16x8*)&qkp2[32];
      }
    }

    f32x4 acc, accB;
    if (wid < 4) {
      acc[0] = b2f(u0c.x); acc[1] = b2f(u0c.y);
      acc[2] = b2f(u0c.z); acc[3] = b2f(u0c.w);
      accB = (f32x4){0.f, 0.f, 0.f, 0.f};
      __builtin_amdgcn_s_setprio(1);
#pragma unroll
      for (int kt = 0; kt < 2; ++kt) {
        bf16x8 sh = *(const bf16x8*)&Sbt_hi[fr][kt * 32 + fq * 8];
        bf16x8 sl = *(const bf16x8*)&Sbt_lo[fr][kt * 32 + fq * 8];
        acc = __builtin_amdgcn_mfma_f32_16x16x32_bf16(fcur[kt], sh, acc, 0, 0, 0);
        acc = __builtin_amdgcn_mfma_f32_16x16x32_bf16(fcur[kt], sl, acc, 0, 0, 0);
      }
#pragma unroll
      for (int kt = 2; kt < 4; ++kt) {
        bf16x8 sh = *(const bf16x8*)&Sbt_hi[fr][kt * 32 + fq * 8];
        bf16x8 sl = *(const bf16x8*)&Sbt_lo[fr][kt * 32 + fq * 8];
        accB = __builtin_amdgcn_mfma_f32_16x16x32_bf16(fcur[kt], sh, accB, 0, 0, 0);
        accB = __builtin_amdgcn_mfma_f32_16x16x32_bf16(fcur[kt], sl, accB, 0, 0, 0);
      }
      __builtin_amdgcn_s_setprio(0);
      ushort4 ub = {f2b(acc[0] + accB[0]), f2b(acc[1] + accB[1]),
                    f2b(acc[2] + accB[2]), f2b(acc[3] + accB[3])};
      *(ushort4*)&Ubt[fr][m0w + fq * 4] = ub;
    } else {
      acc = (f32x4){0.f, 0.f, 0.f, 0.f};
      accB = (f32x4){0.f, 0.f, 0.f, 0.f};
#pragma unroll
      for (int kt = 0; kt < 2; ++kt) {
        bf16x8 sh = *(const bf16x8*)&Sbt_hi[fr][kt * 32 + fq * 8];
        acc = __builtin_amdgcn_mfma_f32_16x16x32_bf16(fcur[kt], sh, acc, 0, 0, 0);
      }
#pragma unroll
      for (int kt = 2; kt < 4; ++kt) {
        bf16x8 sh = *(const bf16x8*)&Sbt_hi[fr][kt * 32 + fq * 8];
        accB = __builtin_amdgcn_mfma_f32_16x16x32_bf16(fcur[kt], sh, accB, 0, 0, 0);
      }
    }
    __syncthreads();

    if (wid >= 4) {
      bf16x8 uf0 = *(const bf16x8*)&Ubt[fr][fq * 8];
      bf16x8 uf1 = *(const bf16x8*)&Ubt[fr][32 + fq * 8];
      acc  = __builtin_amdgcn_mfma_f32_16x16x32_bf16(qkc0, uf0, acc, 0, 0, 0);
      accB = __builtin_amdgcn_mfma_f32_16x16x32_bf16(qkc1, uf1, accB, 0, 0, 0);
      u16* op = uobase + (size_t)(c0 + m0w + fq * 4) * DV + fr;
      op[0] = f2b(acc[0] + accB[0]);
      op[(size_t)DV] = f2b(acc[1] + accB[1]);
      op[(size_t)2 * DV] = f2b(acc[2] + accB[2]);
      op[(size_t)3 * DV] = f2b(acc[3] + accB[3]);
    }
    __builtin_amdgcn_s_setprio(1);
#pragma unroll
    for (int kt = 0; kt < 2; ++kt) {
      bf16x8 kf = *(const bf16x8*)&Kt[16 * wid + fr][kt * 32 + fq * 8];
      bf16x8 uf = *(const bf16x8*)&Ubt[fr][kt * 32 + fq * 8];
      Sfrag = __builtin_amdgcn_mfma_f32_16x16x32_bf16(kf, uf, Sfrag, 0, 0, 0);
    }
    __builtin_amdgcn_s_setprio(0);
    ushort4 shv, slv;
#pragma unroll
    for (int i = 0; i < 4; ++i) {
      float s = Sfrag[i];
      u16 hpart = f2b(s);
      ((u16*)&shv)[i] = hpart;
      ((u16*)&slv)[i] = f2b(s - b2f(hpart));
    }
    *(ushort4*)&Sbt_hi[fr][16 * wid + fq * 4] = shv;
    *(ushort4*)&Sbt_lo[fr][16 * wid + fq * 4] = slv;
    __syncthreads();
  }
}

// ---- 5b standalone scan (fallback) ----
__global__ __launch_bounds__(512) void delta_scan_kernel(
    const u16* __restrict__ qk, const u16* __restrict__ Wb,
    const u16* __restrict__ QKb, u16* uo) {
  __shared__ alignas(16) u16 Kt[128][72];
  __shared__ alignas(16) u16 Sbt_hi[16][136];
  __shared__ alignas(16) u16 Sbt_lo[16][136];
  __shared__ alignas(16) u16 Ubt[16][72];
  scan_body(blockIdx.x, qk, Wb, QKb, uo, Kt, Sbt_hi, Sbt_lo, Ubt);
}

// ---- 5c FUSED: blocks 0-255 scan; 256-1279 Wg GEMM (512 thr, 8 waves) ----
__global__ __launch_bounds__(512) void scan_wg_kernel(
    const u16* __restrict__ qk, const u16* __restrict__ Wb,
    const u16* __restrict__ QKb, u16* uo,
    const u16* __restrict__ A, const u16* __restrict__ BT, u16* __restrict__ C) {
  __shared__ alignas(16) u16 Kt[128][72];
  __shared__ alignas(16) u16 Sbt_hi[16][136];
  __shared__ alignas(16) u16 Sbt_lo[16][136];
  __shared__ alignas(16) u16 Ubt[16][72];
  __shared__ u16 As[128 * 64];
  __shared__ u16 Bs[128 * 64];

  if (blockIdx.x < 256) {
    scan_body(blockIdx.x, qk, Wb, QKb, uo, Kt, Sbt_hi, Sbt_lo, Ubt);
    return;
  }
  const int tid = threadIdx.x;
  const int wid = tid >> 6, lane = tid & 63;
  const int wr = wid >> 2, wc = wid & 3;
  const int fr = lane & 15, fk = lane >> 4;
  const int nbx = DV >> 7;
  const int gbid = blockIdx.x - 256, nwg = 1024;
  const int swz = (gbid & 7) * (nwg >> 3) + (gbid >> 3);
  const int row0 = (swz / nbx) * 128, col0 = (swz % nbx) * 128;

  int sr[2], sk[2];
#pragma unroll
  for (int i = 0; i < 2; ++i) {
    int s = i * 8 + wid;
    int r = s * 8 + (lane >> 3);
    sr[i] = r;
    sk[i] = ((lane & 7) ^ (r & 7)) << 3;
  }

  f32x4 acc[4][2];
#pragma unroll
  for (int i = 0; i < 4; ++i)
#pragma unroll
    for (int j = 0; j < 2; ++j) acc[i][j] = {0.f, 0.f, 0.f, 0.f};

  for (int k0 = 0; k0 < Dm; k0 += 64) {
#pragma unroll
    for (int i = 0; i < 2; ++i) {
      const int s = i * 8 + wid;
      gld16(&A[(size_t)(row0 + sr[i]) * Dm + k0 + sk[i]], &As[s * 512]);
      gld16(&BT[(size_t)(col0 + sr[i]) * Dm + k0 + sk[i]], &Bs[s * 512]);
    }
    __syncthreads();
#pragma unroll
    for (int kt = 0; kt < 2; ++kt) {
      bf16x8 af[4], bf[2];
#pragma unroll
      for (int mi = 0; mi < 4; ++mi) {
        int row = wr * 64 + mi * 16 + fr;
        af[mi] = *(const bf16x8*)&As[row * 64 + (((kt * 4 + fk) ^ (fr & 7)) << 3)];
      }
#pragma unroll
      for (int ni = 0; ni < 2; ++ni) {
        int row = wc * 32 + ni * 16 + fr;
        bf[ni] = *(const bf16x8*)&Bs[row * 64 + (((kt * 4 + fk) ^ (fr & 7)) << 3)];
      }
#pragma unroll
      for (int mi = 0; mi < 4; ++mi)
#pragma unroll
        for (int ni = 0; ni < 2; ++ni)
          acc[mi][ni] = __builtin_amdgcn_mfma_f32_16x16x32_bf16(
              af[mi], bf[ni], acc[mi][ni], 0, 0, 0);
    }
    __syncthreads();
  }
#pragma unroll
  for (int mi = 0; mi < 4; ++mi)
#pragma unroll
    for (int ni = 0; ni < 2; ++ni) {
      int col = col0 + wc * 32 + ni * 16 + fr;
#pragma unroll
      for (int r = 0; r < 4; ++r) {
        int row = row0 + wr * 64 + mi * 16 + fk * 4 + r;
        C[(size_t)row * DV + col] = f2b(acc[mi][ni][r]);
      }
    }
}

// ---- 6. gate ----
__global__ __launch_bounds__(256) void gate_kernel(
    const u16* og, const u16* __restrict__ g,
    const float* __restrict__ nw, u16* out) {
  int idx = blockIdx.x * 4 + (threadIdx.x >> 6), lane = threadIdx.x & 63;
  size_t base = (size_t)(idx >> 2) * DV + (size_t)(idx & 3) * DVH + (size_t)lane * 4;
  ushort4 o4 = *(const ushort4*)&og[base];
  float ox = b2f(o4.x), oy = b2f(o4.y), oz = b2f(o4.z), ow = b2f(o4.w);
  float ss = ox * ox + oy * oy + oz * oz + ow * ow;
#pragma unroll
  for (int off = 32; off; off >>= 1) ss += __shfl_xor(ss, off);
  float r = 1.f / sqrtf(ss * (1.f / DVH) + 1e-5f);
  ushort4 g4 = *(const ushort4*)&g[base];
  float gx = b2f(g4.x), gy = b2f(g4.y), gz = b2f(g4.z), gw = b2f(g4.w);
  float4 wv = *(const float4*)&nw[lane * 4];
  ushort4 res;
  res.x = f2b(ox * r * wv.x * (gx * sig_(gx)));
  res.y = f2b(oy * r * wv.y * (gy * sig_(gy)));
  res.z = f2b(oz * r * wv.z * (gz * sig_(gz)));
  res.w = f2b(ow * r * wv.w * (gw * sig_(gw)));
  *(ushort4*)&out[base] = res;
}

// ---- fallback Wg GEMM (bf16 out) ----
__global__ __launch_bounds__(256) void gemm_bf16_kernel(
    const u16* __restrict__ A, const u16* __restrict__ BT, void* __restrict__ Cv,
    int M, int N, int K) {
  __shared__ u16 As[128 * 64];
  __shared__ u16 Bs[128 * 64];
  gemm_body<0>(A, BT, Cv, M, N, K, blockIdx.x, gridDim.x, As, Bs);
}

// ---- host ----
extern "C" void kernel_launch(void* const* d_in, const int* in_sizes, int n_in,
                              void* d_out, int out_size, void* d_ws, size_t ws_size,
                              hipStream_t stream) {
  (void)in_sizes; (void)n_in; (void)out_size;
  const float* x  = (const float*)d_in[0];
  const float* cw = (const float*)d_in[1];
  const float* Wq = (const float*)d_in[2];
  const float* Wk = (const float*)d_in[3];
  const float* Wv = (const float*)d_in[4];
  const float* Wb = (const float*)d_in[5];
  const float* Wg = (const float*)d_in[6];
  const float* nw = (const float*)d_in[7];
  const float* Wo = (const float*)d_in[8];
  float* out = (float*)d_out;   // f32 output

  u16* hb  = (u16*)d_ws;                       // ROWS*Dm  bf16
  u16* qkb = hb + (size_t)ROWS * Dm;           // ROWS*QKS (q cols 0-511, k 512-1023)
  u16* vb  = qkb + (size_t)ROWS * QKS;         // ROWS*DV  (v -> U0 -> O; gate in-place)
  float* bbuf = (float*)(vb + (size_t)ROWS * DV);   // ROWS*H f32
  u16* Wbuf  = (u16*)(bbuf + (size_t)ROWS * H);     // 16*Lseq*DQH bf16 (negated)
  u16* QKbuf = Wbuf + (size_t)16 * Lseq * DQH;      // 16*Lseq*CH  bf16
  u16* wq16 = QKbuf + (size_t)16 * Lseq * CH;       // [N][K] bf16; wq16||wk16 = combined
  u16* wk16 = wq16 + (size_t)Dm * DK;
  u16* wv16 = wk16 + (size_t)Dm * DK;
  u16* wg16 = wv16 + (size_t)Dm * DV;
  u16* wo16 = wg16 + (size_t)Dm * DV;
  u16* gb2  = wo16 + (size_t)DV * Dm;               // separate g buffer (fused path)
  u16* gb   = qkb;                                  // aliased g buffer (fallback)

  const size_t need = (size_t)ROWS * (Dm + QKS + DV) * 2 + (size_t)ROWS * H * 4
                    + (size_t)16 * Lseq * (DQH + CH) * 2
                    + ((size_t)Dm * (DK * 2 + DV * 3)) * 2;
  const size_t need2 = need + (size_t)ROWS * DV * 2;
  if (ws_size < need) {
    ws_sentinel_kernel<<<1, 1, 0, stream>>>(out, (float)ws_size);
    return;
  }
  const bool fused = (ws_size >= need2);

  prologue_kernel<<<10240, 256, 0, stream>>>(x, cw, hb, Wq, Wk, Wv, Wg, Wo,
                                             wq16, wk16, wv16, wg16, wo16);
  proj_kernel<<<6144, 256, 0, stream>>>(hb, wq16, wv16, Wb, qkb, vb, bbuf);

  delta_prep_kernel<<<1024, 256, 0, stream>>>(qkb, vb, bbuf, Wbuf, QKbuf);

  if (fused) {
    scan_wg_kernel<<<1280, 512, 0, stream>>>(qkb, Wbuf, QKbuf, vb, hb, wg16, gb2);
    gate_kernel<<<ROWS * H / 4, 256, 0, stream>>>(vb, gb2, nw, vb);
  } else {
    delta_scan_kernel<<<256, 512, 0, stream>>>(qkb, Wbuf, QKbuf, vb);
    gemm_bf16_kernel<<<(DV / 128) * (ROWS / 128), 256, 0, stream>>>(hb, wg16, gb, ROWS, DV, Dm);
    gate_kernel<<<ROWS * H / 4, 256, 0, stream>>>(vb, gb, nw, vb);
  }

  gemm_mfma_kernel<<<(Dm / 128) * (ROWS / 128), 256, 0, stream>>>(vb, wo16, out, ROWS, Dm, DV);
}